// Round 16
// baseline (80.756 us; speedup 1.0000x reference)
//
#include <hip/hip_runtime.h>
#include <math.h>

#define Bn 2048
#define Dd 128
#define Cc 50000
#define NSPL 32     // arc col-splits; grid 1024 = 32 row-blocks x 32 splits = 4/CU exact
#define NCH 26      // fixed chunk-loop bound (max ntm = 25)
#define NTILE 782   // ceil(50000/64)
#define TS 32       // triplet col-splits (64 cols each)

#define COS_Mf 0.8775825618903728f
#define SIN_Mf 0.479425538604203f
#define THf (-0.8775825618903728f)
#define MMf 0.2397127693021015f
#define L2E64 92.33248261689366f   // 64 * log2(e)

typedef __attribute__((ext_vector_type(8))) short short8;
typedef __attribute__((ext_vector_type(4))) float f32x4;

__device__ __forceinline__ unsigned short f2bf(float f) {
    unsigned int u = __float_as_uint(f);
    u += 0x7fffu + ((u >> 16) & 1u);
    return (unsigned short)(u >> 16);
}
__device__ __forceinline__ float bf2f(unsigned short h) {
    return __uint_as_float(((unsigned int)h) << 16);
}

// ---------------- row normalization -> bf16, float4-vectorized (8 rows/block) ----------------
__global__ void norm_all(const float* __restrict__ emb, const float* __restrict__ W,
                         unsigned short* __restrict__ embn, unsigned short* __restrict__ rawb,
                         float* __restrict__ sqn, unsigned short* __restrict__ wnb,
                         float* __restrict__ zp) {
    if (blockIdx.x == 0) zp[threadIdx.x] = 0.f;    // esum|wsum (256 floats)
    int wid = threadIdx.x >> 6;
    int lane = threadIdx.x & 63;
    int half = lane >> 5, l32 = lane & 31;
    int row = blockIdx.x * 8 + wid * 2 + half;
    bool ise = row < Bn;
    int r = ise ? row : row - Bn;
    const float* p = (ise ? emb : W) + (size_t)r * Dd + l32 * 4;
    float4 v = *reinterpret_cast<const float4*>(p);
    float ss = v.x * v.x + v.y * v.y + v.z * v.z + v.w * v.w;
    #pragma unroll
    for (int o = 16; o > 0; o >>= 1) ss += __shfl_xor(ss, o);   // stays within 32-lane half
    float rn = rsqrtf(ss);
    ushort4 q4 = make_ushort4(f2bf(v.x * rn), f2bf(v.y * rn), f2bf(v.z * rn), f2bf(v.w * rn));
    *reinterpret_cast<ushort4*>((ise ? embn : wnb) + (size_t)r * Dd + l32 * 4) = q4;
    if (ise) {
        ushort4 r4 = make_ushort4(f2bf(v.x), f2bf(v.y), f2bf(v.z), f2bf(v.w));
        *reinterpret_cast<ushort4*>(rawb + (size_t)r * Dd + l32 * 4) = r4;
        if (l32 == 0) sqn[r] = ss;
    }
}

// ---------------- column sums (blocks 0..271) + per-row label logits (blocks 272..783) ----------------
__global__ void aux_k(const unsigned short* __restrict__ embn,
                      const unsigned short* __restrict__ wnb,
                      const int* __restrict__ lab,
                      float* __restrict__ esum, float* __restrict__ wsum,
                      float* __restrict__ bx, float* __restrict__ tg) {
    __shared__ float s[16][128];
    int t = threadIdx.x;
    if (blockIdx.x < 272) {
        int rg = t >> 4;
        int cg = (t & 15) * 8;
        const unsigned short* src;
        float* dst;
        int r0, rend;
        if (blockIdx.x < 256) {
            src = wnb; dst = wsum;
            r0 = blockIdx.x * 196;
            rend = r0 + 196; if (rend > Cc) rend = Cc;
        } else {
            src = embn; dst = esum;
            r0 = (blockIdx.x - 256) * 128;
            rend = r0 + 128;
        }
        float acc[8];
        #pragma unroll
        for (int j = 0; j < 8; ++j) acc[j] = 0.f;
        for (int r = r0 + rg; r < rend; r += 16) {
            short8 v = *reinterpret_cast<const short8*>(src + (size_t)r * Dd + cg);
            #pragma unroll
            for (int j = 0; j < 8; ++j) acc[j] += bf2f((unsigned short)v[j]);
        }
        #pragma unroll
        for (int j = 0; j < 8; ++j) s[rg][cg + j] = acc[j];
        __syncthreads();
        if (t < 128) {
            float v = 0.f;
            #pragma unroll
            for (int u = 0; u < 16; ++u) v += s[u][t];
            atomicAdd(&dst[t], v);
        }
    } else {
        int wid = t >> 6, lane = t & 63;
        int row = (blockIdx.x - 272) * 4 + wid;
        int lb = lab[row];
        const unsigned short* e = embn + (size_t)row * Dd;
        const unsigned short* wv = wnb + (size_t)lb * Dd;
        float sv = bf2f(e[lane]) * bf2f(wv[lane]) + bf2f(e[lane + 64]) * bf2f(wv[lane + 64]);
        #pragma unroll
        for (int o = 32; o > 0; o >>= 1) sv += __shfl_xor(sv, o);
        if (lane == 0) {
            float c = sv;
            float s2 = fminf(fmaxf(1.f - c * c, 0.f), 1.f);
            float sine = sqrtf(s2);
            float phi = c * COS_Mf - sine * SIN_Mf;
            phi = (c > THf) ? phi : (c - MMf);
            bx[row] = 64.f * c;
            tg[row] = 64.f * phi;
        }
    }
}

// ---------------- fused bf16-MFMA cosine-GEMM + fixed-max softmax partials ----------------
// Per-wave private async pipeline, depth-2, 4 blocks/CU (16 waves/CU), XCD swizzle:
// 1D grid 1024; id = xcd + 8*(rb*4 + sp%4), xcd = sp/4  ->  each XCD hosts 4 of the
// 32 splits (~1.6MB W working set, resident in its 4MB L2). NO __syncthreads in K-loop;
// per-wave counted s_waitcnt vmcnt(4).
__launch_bounds__(256, 4)
__global__ void arc_main(const unsigned short* __restrict__ en,
                         const unsigned short* __restrict__ wn,
                         float* __restrict__ ps) {
    __shared__ unsigned short swb[4][2][2048];   // [wave][buf][16 cols x 128 k], 32KB
    __shared__ float sred[4][64];
    const int t = threadIdx.x;
    const int w = t >> 6, l = t & 63;
    const int id = blockIdx.x;
    const int xcd = id & 7, j = id >> 3;         // j in 0..127
    const int r0 = (j >> 2) * 64;                // row-block 0..31
    const int split = xcd * 4 + (j & 3);         // 0..31
    const int strip = w * 16;                    // wave's 16-col strip within each 64-col tile
    const int lc = l & 15, lk = l >> 4;

    // A panel: 64 rows x 128 k (frag: row=lc, k=lk*8 within kc*32)
    short8 afrag[4][4];
    #pragma unroll
    for (int sm = 0; sm < 4; ++sm)
        #pragma unroll
        for (int kc = 0; kc < 4; ++kc)
            afrag[sm][kc] = *reinterpret_cast<const short8*>(
                en + (size_t)(r0 + sm * 16 + lc) * Dd + kc * 32 + lk * 8);

    float sacc[4][4];
    #pragma unroll
    for (int sm = 0; sm < 4; ++sm)
        #pragma unroll
        for (int r = 0; r < 4; ++r) sacc[sm][r] = 0.f;

    const int ntm = (NTILE - 1 - split) / NSPL + 1;   // 24 or 25

    // loop-invariant per-lane stage offsets (elements); source pre-swizzled (rule-21 pair)
    size_t loff[4];
    #pragma unroll
    for (int jj = 0; jj < 4; ++jj) {
        int colloc = jj * 4 + lk;                // 0..15 local col
        int kb = (lc * 16) ^ ((colloc & 7) << 4);
        loff[jj] = ((size_t)(strip + colloc) << 7) + (kb >> 1);
    }

    auto STAGE = [&](unsigned short* buf, int idx) {
        int tl = split + idx * NSPL;
        if (tl > NTILE - 1) tl = NTILE - 1;
        const unsigned short* tb = wn + ((size_t)tl << 13);   // tile base (uniform)
        #pragma unroll
        for (int jj = 0; jj < 4; ++jj) {
            __builtin_amdgcn_global_load_lds(
                (const __attribute__((address_space(1))) void*)(tb + loff[jj]),
                (__attribute__((address_space(3))) void*)(buf + jj * 512),
                16, 0, 0);
        }
    };

    unsigned short* b0 = &swb[w][0][0];
    unsigned short* b1 = &swb[w][1][0];

    STAGE(b0, 0);
    STAGE(b1, 1);

#define ASTEP(BUF, I) {                                                        \
    if ((I) < ntm) {                                                           \
        asm volatile("s_waitcnt vmcnt(4)" ::: "memory");                       \
        short8 bfr[4];                                                         \
        _Pragma("unroll")                                                      \
        for (int kc = 0; kc < 4; ++kc) {                                       \
            int rkb = (kc * 64 + lk * 16) ^ ((lc & 7) << 4);                   \
            bfr[kc] = *reinterpret_cast<const short8*>(BUF + lc * 128 + (rkb >> 1)); \
        }                                                                      \
        asm volatile("s_waitcnt lgkmcnt(0)" ::: "memory");                     \
        STAGE(BUF, (I) + 2);                                                   \
        f32x4 acc[4];                                                          \
        _Pragma("unroll")                                                      \
        for (int sm = 0; sm < 4; ++sm) acc[sm] = (f32x4){0.f, 0.f, 0.f, 0.f};  \
        _Pragma("unroll")                                                      \
        for (int kc = 0; kc < 4; ++kc)                                         \
            _Pragma("unroll")                                                  \
            for (int sm = 0; sm < 4; ++sm)                                     \
                acc[sm] = __builtin_amdgcn_mfma_f32_16x16x32_bf16(             \
                    afrag[sm][kc], bfr[kc], acc[sm], 0, 0, 0);                 \
        const int c0t = (split + (I) * NSPL) * 64;                             \
        if (c0t + strip < Cc) {                                                \
            _Pragma("unroll")                                                  \
            for (int sm = 0; sm < 4; ++sm)                                     \
                _Pragma("unroll")                                              \
                for (int r = 0; r < 4; ++r)                                    \
                    sacc[sm][r] += __builtin_amdgcn_exp2f(                     \
                        fmaf(acc[sm][r], L2E64, -L2E64));                      \
        }                                                                      \
    } }

    for (int ii = 0; ii < NCH; ii += 2) {
        ASTEP(b0, ii);
        ASTEP(b1, ii + 1);
    }
#undef ASTEP

    // reduce over the wave's 16 col-lanes; C/D layout: col=l&15, row=(l>>4)*4+r
    #pragma unroll
    for (int sm = 0; sm < 4; ++sm)
        #pragma unroll
        for (int r = 0; r < 4; ++r) {
            float v = sacc[sm][r];
            v += __shfl_xor(v, 1); v += __shfl_xor(v, 2);
            v += __shfl_xor(v, 4); v += __shfl_xor(v, 8);
            sacc[sm][r] = v;
        }
    if (lc == 0) {
        #pragma unroll
        for (int sm = 0; sm < 4; ++sm)
            #pragma unroll
            for (int r = 0; r < 4; ++r)
                sred[w][sm * 16 + lk * 4 + r] = sacc[sm][r];
    }
    __syncthreads();
    if (t < 64) {
        float sv = sred[0][t] + sred[1][t] + sred[2][t] + sred[3][t];
        ps[(size_t)split * Bn + r0 + t] = sv;
    }
}

// ---------------- batch-hard triplet: bf16 MFMA self-GEMM + masked max/min ----------------
// (R15-proven version, verbatim)
__launch_bounds__(256, 2)
__global__ void trip_k(const unsigned short* __restrict__ eb, const float* __restrict__ sqn,
                       const int* __restrict__ lab,
                       float* __restrict__ hp, float* __restrict__ hn,
                       float* __restrict__ cnt) {
    __shared__ unsigned short swt[8192];      // 16KB: one 64-col tile, XOR-swizzled
    __shared__ float red[128][2][3];
    const int t = threadIdx.x;
    const int w = t >> 6, l = t & 63;
    const int r0 = blockIdx.x * 128;
    const int split = blockIdx.y;
    const int c0 = split * 64;
    const int rowbase = r0 + (w & 1) * 64;
    const int colb = (w >> 1) * 32;

    #pragma unroll
    for (int j = 0; j < 4; ++j) {
        int col = (w * 4 + j) * 4 + (l >> 4);
        int kb = ((l & 15) * 16) ^ ((col & 7) << 4);
        const unsigned short* src = eb + ((size_t)(c0 + col) << 7) + (kb >> 1);
        __builtin_amdgcn_global_load_lds(
            (const __attribute__((address_space(1))) void*)src,
            (__attribute__((address_space(3))) void*)(&swt[(w * 4 + j) * 512]),
            16, 0, 0);
    }

    short8 afrag[4][4];
    #pragma unroll
    for (int sm = 0; sm < 4; ++sm)
        #pragma unroll
        for (int kc = 0; kc < 4; ++kc) {
            int row = rowbase + sm * 16 + (l & 15);
            int k0 = kc * 32 + (l >> 4) * 8;
            afrag[sm][kc] = *reinterpret_cast<const short8*>(eb + (size_t)row * Dd + k0);
        }

    float rsq[4][4]; int rlb[4][4];
    #pragma unroll
    for (int sm = 0; sm < 4; ++sm)
        #pragma unroll
        for (int r = 0; r < 4; ++r) {
            int row = rowbase + sm * 16 + (l >> 4) * 4 + r;
            rsq[sm][r] = sqn[row];
            rlb[sm][r] = lab[row];
        }
    int cj[2]; float csq[2]; int clb[2];
    #pragma unroll
    for (int sn = 0; sn < 2; ++sn) {
        cj[sn] = c0 + colb + sn * 16 + (l & 15);
        csq[sn] = sqn[cj[sn]];
        clb[sn] = lab[cj[sn]];
    }

    __syncthreads();

    f32x4 acc[4][2];
    #pragma unroll
    for (int sm = 0; sm < 4; ++sm)
        #pragma unroll
        for (int sn = 0; sn < 2; ++sn)
            acc[sm][sn] = (f32x4){0.f, 0.f, 0.f, 0.f};

    #pragma unroll
    for (int kc = 0; kc < 4; ++kc) {
        short8 bfr[2];
        #pragma unroll
        for (int sn = 0; sn < 2; ++sn) {
            int rcol = colb + sn * 16 + (l & 15);
            int rkb = (kc * 64 + (l >> 4) * 16) ^ ((rcol & 7) << 4);
            bfr[sn] = *reinterpret_cast<const short8*>(swt + rcol * 128 + (rkb >> 1));
        }
        #pragma unroll
        for (int sn = 0; sn < 2; ++sn)
            #pragma unroll
            for (int sm = 0; sm < 4; ++sm)
                acc[sm][sn] = __builtin_amdgcn_mfma_f32_16x16x32_bf16(
                    afrag[sm][kc], bfr[sn], acc[sm][sn], 0, 0, 0);
    }

    float vhp[4][4], vhn[4][4], vct[4][4];
    #pragma unroll
    for (int sm = 0; sm < 4; ++sm)
        #pragma unroll
        for (int r = 0; r < 4; ++r) { vhp[sm][r] = 0.f; vhn[sm][r] = 1e30f; vct[sm][r] = 0.f; }

    #pragma unroll
    for (int sm = 0; sm < 4; ++sm)
        #pragma unroll
        for (int r = 0; r < 4; ++r) {
            int rg = rowbase + sm * 16 + (l >> 4) * 4 + r;
            #pragma unroll
            for (int sn = 0; sn < 2; ++sn) {
                float d2 = fmaf(acc[sm][sn][r], -2.f, rsq[sm][r] + csq[sn]);
                float dist = sqrtf(fmaxf(d2, 0.f) + 1e-16f);
                bool same = (rlb[sm][r] == clb[sn]);
                bool psel = same && (rg != cj[sn]);
                if (psel) { vhp[sm][r] = fmaxf(vhp[sm][r], dist); vct[sm][r] += 1.f; }
                if (!same) vhn[sm][r] = fminf(vhn[sm][r], dist);
            }
        }

    #pragma unroll
    for (int sm = 0; sm < 4; ++sm)
        #pragma unroll
        for (int r = 0; r < 4; ++r) {
            float a = vhp[sm][r], b = vhn[sm][r], c = vct[sm][r];
            #pragma unroll
            for (int o = 1; o < 16; o <<= 1) {
                a = fmaxf(a, __shfl_xor(a, o));
                b = fminf(b, __shfl_xor(b, o));
                c += __shfl_xor(c, o);
            }
            if ((l & 15) == 0) {
                int row = (w & 1) * 64 + sm * 16 + (l >> 4) * 4 + r;
                red[row][w >> 1][0] = a;
                red[row][w >> 1][1] = b;
                red[row][w >> 1][2] = c;
            }
        }
    __syncthreads();
    if (t < 128) {
        float a = fmaxf(red[t][0][0], red[t][1][0]);
        float b = fminf(red[t][0][1], red[t][1][1]);
        float c = red[t][0][2] + red[t][1][2];
        hp[(size_t)split * Bn + r0 + t] = a;
        hn[(size_t)split * Bn + r0 + t] = b;
        cnt[(size_t)split * Bn + r0 + t] = c;
    }
}

// ---------------- per-row merge -> per-block partials (32 blocks, 4 lanes/row) ----------------
__launch_bounds__(256)
__global__ void final_k(const float* __restrict__ ps, const float* __restrict__ bx,
                        const float* __restrict__ tg, const float* __restrict__ hp,
                        const float* __restrict__ hn, const float* __restrict__ cnt,
                        float* __restrict__ gpart) {
    __shared__ float sA[4], sT[4], sV[4];
    int t = threadIdx.x;
    int row = blockIdx.x * 64 + (t >> 2);
    int part = t & 3;
    float s = 0.f;
    for (int u = part; u < NSPL; u += 4) s += ps[(size_t)u * Bn + row];
    float a = 0.f, b = 1e30f, c = 0.f;
    for (int u = part; u < TS; u += 4) {
        a = fmaxf(a, hp[(size_t)u * Bn + row]);
        b = fminf(b, hn[(size_t)u * Bn + row]);
        c += cnt[(size_t)u * Bn + row];
    }
    // combine the 4 row-parts (lanes p, p^1, p^2 within aligned 4-lane group)
    s += __shfl_xor(s, 1); s += __shfl_xor(s, 2);
    a = fmaxf(a, __shfl_xor(a, 1)); a = fmaxf(a, __shfl_xor(a, 2));
    b = fminf(b, __shfl_xor(b, 1)); b = fminf(b, __shfl_xor(b, 2));
    c += __shfl_xor(c, 1); c += __shfl_xor(c, 2);

    float arcs = 0.f, tris = 0.f, vals = 0.f;
    if (part == 0) {
        float base = bx[row], targ = tg[row];
        s += __expf(targ - 64.f) - __expf(base - 64.f);
        float lse = 64.f + logf(s);
        arcs = lse - 0.9f * targ - 0.1f * (targ - base) / (float)Cc;
        float tl = fmaxf(a - b + 0.3f, 0.f);
        tris = (c > 0.f) ? tl : 0.f;
        vals = (c > 0.f) ? 1.f : 0.f;
    }

    #pragma unroll
    for (int o = 32; o > 0; o >>= 1) {
        arcs += __shfl_xor(arcs, o);
        tris += __shfl_xor(tris, o);
        vals += __shfl_xor(vals, o);
    }
    int wid = t >> 6, lane = t & 63;
    if (lane == 0) { sA[wid] = arcs; sT[wid] = tris; sV[wid] = vals; }
    __syncthreads();
    if (t == 0) {
        gpart[blockIdx.x * 3 + 0] = sA[0] + sA[1] + sA[2] + sA[3];
        gpart[blockIdx.x * 3 + 1] = sT[0] + sT[1] + sT[2] + sT[3];
        gpart[blockIdx.x * 3 + 2] = sV[0] + sV[1] + sV[2] + sV[3];
    }
}

// ---------------- scalar finish ----------------
__global__ void final2_k(const float* __restrict__ gpart, const float* __restrict__ es,
                         const float* __restrict__ wsum, float* __restrict__ out) {
    int l = threadIdx.x;   // 64
    float x = es[l] * wsum[l] + es[l + 64] * wsum[l + 64];
    #pragma unroll
    for (int o = 32; o > 0; o >>= 1) x += __shfl_xor(x, o);
    if (l == 0) {
        float A = 0.f, T = 0.f, V = 0.f;
        for (int b = 0; b < 32; ++b) {
            A += gpart[b * 3 + 0];
            T += gpart[b * 3 + 1];
            V += gpart[b * 3 + 2];
        }
        float tri = (V > 0.f) ? (T / fmaxf(V, 1.f)) : 0.f;
        out[0] = (A - 6.4f * x / (float)Cc) / (float)Bn + 0.5f * tri;
    }
}

extern "C" void kernel_launch(void* const* d_in, const int* in_sizes, int n_in,
                              void* d_out, int out_size, void* d_ws, size_t ws_size,
                              hipStream_t stream) {
    const float* emb = (const float*)d_in[0];
    const float* W = (const float*)d_in[1];
    const int* lab = (const int*)d_in[2];
    float* out = (float*)d_out;

    unsigned short* embn = (unsigned short*)d_ws;          // 2048*128 bf16
    unsigned short* rawb = embn + (size_t)Bn * Dd;         // 2048*128 bf16
    unsigned short* wnb = rawb + (size_t)Bn * Dd;          // 50000*128 bf16
    float* sqn = (float*)(wnb + (size_t)Cc * Dd);          // 2048
    float* ps = sqn + Bn;                                  // NSPL*2048
    float* bx = ps + (size_t)NSPL * Bn;                    // 2048
    float* tg = bx + Bn;                                   // 2048
    float* hp = tg + Bn;                                   // TS*2048
    float* hn = hp + (size_t)TS * Bn;                      // TS*2048
    float* ct = hn + (size_t)TS * Bn;                      // TS*2048
    float* esum = ct + (size_t)TS * Bn;                    // 128
    float* wsum = esum + 128;                              // 128
    float* gpart = wsum + 128;                             // 96

    norm_all<<<256 + Cc / 8, 256, 0, stream>>>(emb, W, embn, rawb, sqn, wnb, esum);
    aux_k<<<272 + Bn / 4, 256, 0, stream>>>(embn, wnb, lab, esum, wsum, bx, tg);
    arc_main<<<1024, 256, 0, stream>>>(embn, wnb, ps);
    trip_k<<<dim3(16, TS), 256, 0, stream>>>(rawb, sqn, lab, hp, hn, ct);
    final_k<<<32, 256, 0, stream>>>(ps, bx, tg, hp, hn, ct, gpart);
    final2_k<<<1, 64, 0, stream>>>(gpart, esum, wsum, out);
}

// Round 17
// 71.851 us; speedup vs baseline: 1.1239x; 1.1239x over previous
//
#include <hip/hip_runtime.h>
#include <math.h>

#define Bn 2048
#define Dd 128
#define Cc 50000
#define NSPL 24     // arc col-splits; grid 768 = 32 row-blocks x 24 splits = 3/CU exact
#define NTILE 782   // ceil(50000/64)
#define TS 32       // triplet col-splits (64 cols each)

#define COS_Mf 0.8775825618903728f
#define SIN_Mf 0.479425538604203f
#define THf (-0.8775825618903728f)
#define MMf 0.2397127693021015f
#define L2E64 92.33248261689366f   // 64 * log2(e)

typedef __attribute__((ext_vector_type(8))) short short8;
typedef __attribute__((ext_vector_type(4))) float f32x4;

__device__ __forceinline__ unsigned short f2bf(float f) {
    unsigned int u = __float_as_uint(f);
    u += 0x7fffu + ((u >> 16) & 1u);
    return (unsigned short)(u >> 16);
}
__device__ __forceinline__ float bf2f(unsigned short h) {
    return __uint_as_float(((unsigned int)h) << 16);
}

// ---------------- row normalization -> bf16, float4-vectorized (8 rows/block) ----------------
__global__ void norm_all(const float* __restrict__ emb, const float* __restrict__ W,
                         unsigned short* __restrict__ embn, unsigned short* __restrict__ rawb,
                         float* __restrict__ sqn, unsigned short* __restrict__ wnb,
                         float* __restrict__ zp) {
    if (blockIdx.x == 0) zp[threadIdx.x] = 0.f;    // esum|wsum (256 floats)
    int wid = threadIdx.x >> 6;
    int lane = threadIdx.x & 63;
    int half = lane >> 5, l32 = lane & 31;
    int row = blockIdx.x * 8 + wid * 2 + half;
    bool ise = row < Bn;
    int r = ise ? row : row - Bn;
    const float* p = (ise ? emb : W) + (size_t)r * Dd + l32 * 4;
    float4 v = *reinterpret_cast<const float4*>(p);
    float ss = v.x * v.x + v.y * v.y + v.z * v.z + v.w * v.w;
    #pragma unroll
    for (int o = 16; o > 0; o >>= 1) ss += __shfl_xor(ss, o);   // stays within 32-lane half
    float rn = rsqrtf(ss);
    ushort4 q4 = make_ushort4(f2bf(v.x * rn), f2bf(v.y * rn), f2bf(v.z * rn), f2bf(v.w * rn));
    *reinterpret_cast<ushort4*>((ise ? embn : wnb) + (size_t)r * Dd + l32 * 4) = q4;
    if (ise) {
        ushort4 r4 = make_ushort4(f2bf(v.x), f2bf(v.y), f2bf(v.z), f2bf(v.w));
        *reinterpret_cast<ushort4*>(rawb + (size_t)r * Dd + l32 * 4) = r4;
        if (l32 == 0) sqn[r] = ss;
    }
}

// ---------------- merged: colsum+target (blocks 0..783) | triplet (blocks 784..1295) ----------------
struct AuxS { float s[16][128]; };                                  //  8 KB
struct TripS { unsigned short swt[8192]; float red[128][2][3]; };   // 19 KB

__launch_bounds__(256, 2)
__global__ void mid_k(const unsigned short* __restrict__ embn,
                      const unsigned short* __restrict__ wnb,
                      const int* __restrict__ lab,
                      float* __restrict__ esum, float* __restrict__ wsum,
                      float* __restrict__ bx, float* __restrict__ tg,
                      const unsigned short* __restrict__ eb, const float* __restrict__ sqn,
                      float* __restrict__ hp, float* __restrict__ hn,
                      float* __restrict__ cnt) {
    __shared__ __align__(16) char smem[sizeof(TripS)];
    const int bid = blockIdx.x;
    const int t = threadIdx.x;

    if (bid < 784) {
        // ===== aux: column sums (0..271) + per-row label logits (272..783), verbatim =====
        AuxS& S = *reinterpret_cast<AuxS*>(smem);
        if (bid < 272) {
            int rg = t >> 4;
            int cg = (t & 15) * 8;
            const unsigned short* src;
            float* dst;
            int r0, rend;
            if (bid < 256) {
                src = wnb; dst = wsum;
                r0 = bid * 196;
                rend = r0 + 196; if (rend > Cc) rend = Cc;
            } else {
                src = embn; dst = esum;
                r0 = (bid - 256) * 128;
                rend = r0 + 128;
            }
            float acc[8];
            #pragma unroll
            for (int j = 0; j < 8; ++j) acc[j] = 0.f;
            for (int r = r0 + rg; r < rend; r += 16) {
                short8 v = *reinterpret_cast<const short8*>(src + (size_t)r * Dd + cg);
                #pragma unroll
                for (int j = 0; j < 8; ++j) acc[j] += bf2f((unsigned short)v[j]);
            }
            #pragma unroll
            for (int j = 0; j < 8; ++j) S.s[rg][cg + j] = acc[j];
            __syncthreads();
            if (t < 128) {
                float v = 0.f;
                #pragma unroll
                for (int u = 0; u < 16; ++u) v += S.s[u][t];
                atomicAdd(&dst[t], v);
            }
        } else {
            int wid = t >> 6, lane = t & 63;
            int row = (bid - 272) * 4 + wid;
            int lb = lab[row];
            const unsigned short* e = embn + (size_t)row * Dd;
            const unsigned short* wv = wnb + (size_t)lb * Dd;
            float sv = bf2f(e[lane]) * bf2f(wv[lane]) + bf2f(e[lane + 64]) * bf2f(wv[lane + 64]);
            #pragma unroll
            for (int o = 32; o > 0; o >>= 1) sv += __shfl_xor(sv, o);
            if (lane == 0) {
                float c = sv;
                float s2 = fminf(fmaxf(1.f - c * c, 0.f), 1.f);
                float sine = sqrtf(s2);
                float phi = c * COS_Mf - sine * SIN_Mf;
                phi = (c > THf) ? phi : (c - MMf);
                bx[row] = 64.f * c;
                tg[row] = 64.f * phi;
            }
        }
    } else {
        // ===== triplet: bf16 MFMA self-GEMM + masked max/min (R15 trip_k, verbatim) =====
        TripS& S = *reinterpret_cast<TripS*>(smem);
        const int tb = bid - 784;
        const int w = t >> 6, l = t & 63;
        const int r0 = (tb & 15) * 128;
        const int split = tb >> 4;
        const int c0 = split * 64;
        const int rowbase = r0 + (w & 1) * 64;
        const int colb = (w >> 1) * 32;

        #pragma unroll
        for (int j = 0; j < 4; ++j) {
            int col = (w * 4 + j) * 4 + (l >> 4);
            int kb = ((l & 15) * 16) ^ ((col & 7) << 4);
            const unsigned short* src = eb + ((size_t)(c0 + col) << 7) + (kb >> 1);
            __builtin_amdgcn_global_load_lds(
                (const __attribute__((address_space(1))) void*)src,
                (__attribute__((address_space(3))) void*)(&S.swt[(w * 4 + j) * 512]),
                16, 0, 0);
        }

        short8 afrag[4][4];
        #pragma unroll
        for (int sm = 0; sm < 4; ++sm)
            #pragma unroll
            for (int kc = 0; kc < 4; ++kc) {
                int row = rowbase + sm * 16 + (l & 15);
                int k0 = kc * 32 + (l >> 4) * 8;
                afrag[sm][kc] = *reinterpret_cast<const short8*>(eb + (size_t)row * Dd + k0);
            }

        float rsq[4][4]; int rlb[4][4];
        #pragma unroll
        for (int sm = 0; sm < 4; ++sm)
            #pragma unroll
            for (int r = 0; r < 4; ++r) {
                int row = rowbase + sm * 16 + (l >> 4) * 4 + r;
                rsq[sm][r] = sqn[row];
                rlb[sm][r] = lab[row];
            }
        int cj[2]; float csq[2]; int clb[2];
        #pragma unroll
        for (int sn = 0; sn < 2; ++sn) {
            cj[sn] = c0 + colb + sn * 16 + (l & 15);
            csq[sn] = sqn[cj[sn]];
            clb[sn] = lab[cj[sn]];
        }

        __syncthreads();

        f32x4 acc[4][2];
        #pragma unroll
        for (int sm = 0; sm < 4; ++sm)
            #pragma unroll
            for (int sn = 0; sn < 2; ++sn)
                acc[sm][sn] = (f32x4){0.f, 0.f, 0.f, 0.f};

        #pragma unroll
        for (int kc = 0; kc < 4; ++kc) {
            short8 bfr[2];
            #pragma unroll
            for (int sn = 0; sn < 2; ++sn) {
                int rcol = colb + sn * 16 + (l & 15);
                int rkb = (kc * 64 + (l >> 4) * 16) ^ ((rcol & 7) << 4);
                bfr[sn] = *reinterpret_cast<const short8*>(S.swt + rcol * 128 + (rkb >> 1));
            }
            #pragma unroll
            for (int sn = 0; sn < 2; ++sn)
                #pragma unroll
                for (int sm = 0; sm < 4; ++sm)
                    acc[sm][sn] = __builtin_amdgcn_mfma_f32_16x16x32_bf16(
                        afrag[sm][kc], bfr[sn], acc[sm][sn], 0, 0, 0);
        }

        float vhp[4][4], vhn[4][4], vct[4][4];
        #pragma unroll
        for (int sm = 0; sm < 4; ++sm)
            #pragma unroll
            for (int r = 0; r < 4; ++r) { vhp[sm][r] = 0.f; vhn[sm][r] = 1e30f; vct[sm][r] = 0.f; }

        #pragma unroll
        for (int sm = 0; sm < 4; ++sm)
            #pragma unroll
            for (int r = 0; r < 4; ++r) {
                int rg = rowbase + sm * 16 + (l >> 4) * 4 + r;
                #pragma unroll
                for (int sn = 0; sn < 2; ++sn) {
                    float d2 = fmaf(acc[sm][sn][r], -2.f, rsq[sm][r] + csq[sn]);
                    float dist = sqrtf(fmaxf(d2, 0.f) + 1e-16f);
                    bool same = (rlb[sm][r] == clb[sn]);
                    bool psel = same && (rg != cj[sn]);
                    if (psel) { vhp[sm][r] = fmaxf(vhp[sm][r], dist); vct[sm][r] += 1.f; }
                    if (!same) vhn[sm][r] = fminf(vhn[sm][r], dist);
                }
            }

        #pragma unroll
        for (int sm = 0; sm < 4; ++sm)
            #pragma unroll
            for (int r = 0; r < 4; ++r) {
                float a = vhp[sm][r], b = vhn[sm][r], c = vct[sm][r];
                #pragma unroll
                for (int o = 1; o < 16; o <<= 1) {
                    a = fmaxf(a, __shfl_xor(a, o));
                    b = fminf(b, __shfl_xor(b, o));
                    c += __shfl_xor(c, o);
                }
                if ((l & 15) == 0) {
                    int row = (w & 1) * 64 + sm * 16 + (l >> 4) * 4 + r;
                    S.red[row][w >> 1][0] = a;
                    S.red[row][w >> 1][1] = b;
                    S.red[row][w >> 1][2] = c;
                }
            }
        __syncthreads();
        if (t < 128) {
            float a = fmaxf(S.red[t][0][0], S.red[t][1][0]);
            float b = fminf(S.red[t][0][1], S.red[t][1][1]);
            float c = S.red[t][0][2] + S.red[t][1][2];
            hp[(size_t)split * Bn + r0 + t] = a;
            hn[(size_t)split * Bn + r0 + t] = b;
            cnt[(size_t)split * Bn + r0 + t] = c;
        }
    }
}

// ---------------- fused bf16-MFMA cosine-GEMM + fixed-max softmax partials ----------------
// (R15-proven version, verbatim: depth-3 per-wave private pipeline + XCD swizzle)
__launch_bounds__(256, 3)
__global__ void arc_main(const unsigned short* __restrict__ en,
                         const unsigned short* __restrict__ wn,
                         float* __restrict__ ps) {
    __shared__ unsigned short swb[4][3][2048];   // [wave][buf][16 cols x 128 k], 48KB
    __shared__ float sred[4][64];
    const int t = threadIdx.x;
    const int w = t >> 6, l = t & 63;
    const int id = blockIdx.x;
    const int xcd = id & 7, j = id >> 3;         // j in 0..95
    const int r0 = (j / 3) * 64;                 // row-block 0..31
    const int split = xcd * 3 + (j % 3);         // 0..23
    const int strip = w * 16;                    // wave's 16-col strip within each 64-col tile
    const int lc = l & 15, lk = l >> 4;

    short8 afrag[4][4];
    #pragma unroll
    for (int sm = 0; sm < 4; ++sm)
        #pragma unroll
        for (int kc = 0; kc < 4; ++kc)
            afrag[sm][kc] = *reinterpret_cast<const short8*>(
                en + (size_t)(r0 + sm * 16 + lc) * Dd + kc * 32 + lk * 8);

    float sacc[4][4];
    #pragma unroll
    for (int sm = 0; sm < 4; ++sm)
        #pragma unroll
        for (int r = 0; r < 4; ++r) sacc[sm][r] = 0.f;

    const int ntm = (NTILE - 1 - split) / NSPL + 1;   // 32 or 33

    size_t loff[4];
    #pragma unroll
    for (int jj = 0; jj < 4; ++jj) {
        int colloc = jj * 4 + lk;
        int kb = (lc * 16) ^ ((colloc & 7) << 4);
        loff[jj] = ((size_t)(strip + colloc) << 7) + (kb >> 1);
    }

    auto STAGE = [&](unsigned short* buf, int idx) {
        int tl = split + idx * NSPL;
        if (tl > NTILE - 1) tl = NTILE - 1;
        const unsigned short* tb = wn + ((size_t)tl << 13);
        #pragma unroll
        for (int jj = 0; jj < 4; ++jj) {
            __builtin_amdgcn_global_load_lds(
                (const __attribute__((address_space(1))) void*)(tb + loff[jj]),
                (__attribute__((address_space(3))) void*)(buf + jj * 512),
                16, 0, 0);
        }
    };

    unsigned short* b0 = &swb[w][0][0];
    unsigned short* b1 = &swb[w][1][0];
    unsigned short* b2 = &swb[w][2][0];

    STAGE(b0, 0);
    STAGE(b1, 1);
    STAGE(b2, 2);

#define ASTEP(BUF, I) {                                                        \
    if ((I) < ntm) {                                                           \
        asm volatile("s_waitcnt vmcnt(8)" ::: "memory");                       \
        short8 bfr[4];                                                         \
        _Pragma("unroll")                                                      \
        for (int kc = 0; kc < 4; ++kc) {                                       \
            int rkb = (kc * 64 + lk * 16) ^ ((lc & 7) << 4);                   \
            bfr[kc] = *reinterpret_cast<const short8*>(BUF + lc * 128 + (rkb >> 1)); \
        }                                                                      \
        asm volatile("s_waitcnt lgkmcnt(0)" ::: "memory");                     \
        STAGE(BUF, (I) + 3);                                                   \
        f32x4 acc[4];                                                          \
        _Pragma("unroll")                                                      \
        for (int sm = 0; sm < 4; ++sm) acc[sm] = (f32x4){0.f, 0.f, 0.f, 0.f};  \
        _Pragma("unroll")                                                      \
        for (int kc = 0; kc < 4; ++kc)                                         \
            _Pragma("unroll")                                                  \
            for (int sm = 0; sm < 4; ++sm)                                     \
                acc[sm] = __builtin_amdgcn_mfma_f32_16x16x32_bf16(             \
                    afrag[sm][kc], bfr[kc], acc[sm], 0, 0, 0);                 \
        const int c0t = (split + (I) * NSPL) * 64;                             \
        if (c0t + strip < Cc) {                                                \
            _Pragma("unroll")                                                  \
            for (int sm = 0; sm < 4; ++sm)                                     \
                _Pragma("unroll")                                              \
                for (int r = 0; r < 4; ++r)                                    \
                    sacc[sm][r] += __builtin_amdgcn_exp2f(                     \
                        fmaf(acc[sm][r], L2E64, -L2E64));                      \
        }                                                                      \
    } }

    for (int ii = 0; ii < 33; ii += 3) {
        ASTEP(b0, ii);
        ASTEP(b1, ii + 1);
        ASTEP(b2, ii + 2);
    }
#undef ASTEP

    #pragma unroll
    for (int sm = 0; sm < 4; ++sm)
        #pragma unroll
        for (int r = 0; r < 4; ++r) {
            float v = sacc[sm][r];
            v += __shfl_xor(v, 1); v += __shfl_xor(v, 2);
            v += __shfl_xor(v, 4); v += __shfl_xor(v, 8);
            sacc[sm][r] = v;
        }
    if (lc == 0) {
        #pragma unroll
        for (int sm = 0; sm < 4; ++sm)
            #pragma unroll
            for (int r = 0; r < 4; ++r)
                sred[w][sm * 16 + lk * 4 + r] = sacc[sm][r];
    }
    __syncthreads();
    if (t < 64) {
        float sv = sred[0][t] + sred[1][t] + sred[2][t] + sred[3][t];
        ps[(size_t)split * Bn + r0 + t] = sv;
    }
}

// ---------------- per-row merge -> per-block partials (32 blocks, 4 lanes/row) ----------------
__launch_bounds__(256)
__global__ void final_k(const float* __restrict__ ps, const float* __restrict__ bx,
                        const float* __restrict__ tg, const float* __restrict__ hp,
                        const float* __restrict__ hn, const float* __restrict__ cnt,
                        float* __restrict__ gpart) {
    __shared__ float sA[4], sT[4], sV[4];
    int t = threadIdx.x;
    int row = blockIdx.x * 64 + (t >> 2);
    int part = t & 3;
    float s = 0.f;
    for (int u = part; u < NSPL; u += 4) s += ps[(size_t)u * Bn + row];
    float a = 0.f, b = 1e30f, c = 0.f;
    for (int u = part; u < TS; u += 4) {
        a = fmaxf(a, hp[(size_t)u * Bn + row]);
        b = fminf(b, hn[(size_t)u * Bn + row]);
        c += cnt[(size_t)u * Bn + row];
    }
    s += __shfl_xor(s, 1); s += __shfl_xor(s, 2);
    a = fmaxf(a, __shfl_xor(a, 1)); a = fmaxf(a, __shfl_xor(a, 2));
    b = fminf(b, __shfl_xor(b, 1)); b = fminf(b, __shfl_xor(b, 2));
    c += __shfl_xor(c, 1); c += __shfl_xor(c, 2);

    float arcs = 0.f, tris = 0.f, vals = 0.f;
    if (part == 0) {
        float base = bx[row], targ = tg[row];
        s += __expf(targ - 64.f) - __expf(base - 64.f);
        float lse = 64.f + logf(s);
        arcs = lse - 0.9f * targ - 0.1f * (targ - base) / (float)Cc;
        float tl = fmaxf(a - b + 0.3f, 0.f);
        tris = (c > 0.f) ? tl : 0.f;
        vals = (c > 0.f) ? 1.f : 0.f;
    }

    #pragma unroll
    for (int o = 32; o > 0; o >>= 1) {
        arcs += __shfl_xor(arcs, o);
        tris += __shfl_xor(tris, o);
        vals += __shfl_xor(vals, o);
    }
    int wid = t >> 6, lane = t & 63;
    if (lane == 0) { sA[wid] = arcs; sT[wid] = tris; sV[wid] = vals; }
    __syncthreads();
    if (t == 0) {
        gpart[blockIdx.x * 3 + 0] = sA[0] + sA[1] + sA[2] + sA[3];
        gpart[blockIdx.x * 3 + 1] = sT[0] + sT[1] + sT[2] + sT[3];
        gpart[blockIdx.x * 3 + 2] = sV[0] + sV[1] + sV[2] + sV[3];
    }
}

// ---------------- scalar finish ----------------
__global__ void final2_k(const float* __restrict__ gpart, const float* __restrict__ es,
                         const float* __restrict__ wsum, float* __restrict__ out) {
    int l = threadIdx.x;   // 64
    float x = es[l] * wsum[l] + es[l + 64] * wsum[l + 64];
    #pragma unroll
    for (int o = 32; o > 0; o >>= 1) x += __shfl_xor(x, o);
    if (l == 0) {
        float A = 0.f, T = 0.f, V = 0.f;
        for (int b = 0; b < 32; ++b) {
            A += gpart[b * 3 + 0];
            T += gpart[b * 3 + 1];
            V += gpart[b * 3 + 2];
        }
        float tri = (V > 0.f) ? (T / fmaxf(V, 1.f)) : 0.f;
        out[0] = (A - 6.4f * x / (float)Cc) / (float)Bn + 0.5f * tri;
    }
}

extern "C" void kernel_launch(void* const* d_in, const int* in_sizes, int n_in,
                              void* d_out, int out_size, void* d_ws, size_t ws_size,
                              hipStream_t stream) {
    const float* emb = (const float*)d_in[0];
    const float* W = (const float*)d_in[1];
    const int* lab = (const int*)d_in[2];
    float* out = (float*)d_out;

    unsigned short* embn = (unsigned short*)d_ws;          // 2048*128 bf16
    unsigned short* rawb = embn + (size_t)Bn * Dd;         // 2048*128 bf16
    unsigned short* wnb = rawb + (size_t)Bn * Dd;          // 50000*128 bf16
    float* sqn = (float*)(wnb + (size_t)Cc * Dd);          // 2048
    float* ps = sqn + Bn;                                  // NSPL*2048
    float* bx = ps + (size_t)NSPL * Bn;                    // 2048
    float* tg = bx + Bn;                                   // 2048
    float* hp = tg + Bn;                                   // TS*2048
    float* hn = hp + (size_t)TS * Bn;                      // TS*2048
    float* ct = hn + (size_t)TS * Bn;                      // TS*2048
    float* esum = ct + (size_t)TS * Bn;                    // 128
    float* wsum = esum + 128;                              // 128
    float* gpart = wsum + 128;                             // 96

    norm_all<<<256 + Cc / 8, 256, 0, stream>>>(emb, W, embn, rawb, sqn, wnb, esum);
    mid_k<<<784 + 512, 256, 0, stream>>>(embn, wnb, lab, esum, wsum, bx, tg,
                                         rawb, sqn, hp, hn, ct);
    arc_main<<<768, 256, 0, stream>>>(embn, wnb, ps);
    final_k<<<32, 256, 0, stream>>>(ps, bx, tg, hp, hn, ct, gpart);
    final2_k<<<1, 64, 0, stream>>>(gpart, esum, wsum, out);
}

// Round 18
// 70.846 us; speedup vs baseline: 1.1399x; 1.0142x over previous
//
#include <hip/hip_runtime.h>
#include <math.h>

#define Bn 2048
#define Dd 128
#define Cc 50000
#define NSPL 24     // arc col-splits; grid 768 = 32 row-blocks x 24 splits = 3/CU exact
#define NTILE 782   // ceil(50000/64)
#define TS 32       // triplet col-splits (64 cols each)

#define COS_Mf 0.8775825618903728f
#define SIN_Mf 0.479425538604203f
#define THf (-0.8775825618903728f)
#define MMf 0.2397127693021015f
#define L2E64 92.33248261689366f   // 64 * log2(e)

typedef __attribute__((ext_vector_type(8))) short short8;
typedef __attribute__((ext_vector_type(4))) float f32x4;

__device__ __forceinline__ unsigned short f2bf(float f) {
    unsigned int u = __float_as_uint(f);
    u += 0x7fffu + ((u >> 16) & 1u);
    return (unsigned short)(u >> 16);
}
__device__ __forceinline__ float bf2f(unsigned short h) {
    return __uint_as_float(((unsigned int)h) << 16);
}

// ---------------- row normalization -> bf16, float4-vectorized (8 rows/block) ----------------
__global__ void norm_all(const float* __restrict__ emb, const float* __restrict__ W,
                         unsigned short* __restrict__ embn, unsigned short* __restrict__ rawb,
                         float* __restrict__ sqn, unsigned short* __restrict__ wnb,
                         float* __restrict__ zp, unsigned int* __restrict__ done_ct) {
    if (blockIdx.x == 0) {
        zp[threadIdx.x] = 0.f;                     // esum|wsum (256 floats)
        if (threadIdx.x == 0) *done_ct = 0u;       // last-block counter for final_k
    }
    int wid = threadIdx.x >> 6;
    int lane = threadIdx.x & 63;
    int half = lane >> 5, l32 = lane & 31;
    int row = blockIdx.x * 8 + wid * 2 + half;
    bool ise = row < Bn;
    int r = ise ? row : row - Bn;
    const float* p = (ise ? emb : W) + (size_t)r * Dd + l32 * 4;
    float4 v = *reinterpret_cast<const float4*>(p);
    float ss = v.x * v.x + v.y * v.y + v.z * v.z + v.w * v.w;
    #pragma unroll
    for (int o = 16; o > 0; o >>= 1) ss += __shfl_xor(ss, o);   // stays within 32-lane half
    float rn = rsqrtf(ss);
    ushort4 q4 = make_ushort4(f2bf(v.x * rn), f2bf(v.y * rn), f2bf(v.z * rn), f2bf(v.w * rn));
    *reinterpret_cast<ushort4*>((ise ? embn : wnb) + (size_t)r * Dd + l32 * 4) = q4;
    if (ise) {
        ushort4 r4 = make_ushort4(f2bf(v.x), f2bf(v.y), f2bf(v.z), f2bf(v.w));
        *reinterpret_cast<ushort4*>(rawb + (size_t)r * Dd + l32 * 4) = r4;
        if (l32 == 0) sqn[r] = ss;
    }
}

// ---------------- merged: colsum+target (blocks 0..783) | triplet (blocks 784..1295) ----------------
struct AuxS { float s[16][128]; };                                  //  8 KB
struct TripS { unsigned short swt[8192]; float red[128][2][3]; };   // 19 KB

__launch_bounds__(256, 2)
__global__ void mid_k(const unsigned short* __restrict__ embn,
                      const unsigned short* __restrict__ wnb,
                      const int* __restrict__ lab,
                      float* __restrict__ esum, float* __restrict__ wsum,
                      float* __restrict__ bx, float* __restrict__ tg,
                      const unsigned short* __restrict__ eb, const float* __restrict__ sqn,
                      float* __restrict__ hp, float* __restrict__ hn,
                      float* __restrict__ cnt) {
    __shared__ __align__(16) char smem[sizeof(TripS)];
    const int bid = blockIdx.x;
    const int t = threadIdx.x;

    if (bid < 784) {
        // ===== aux: column sums (0..271) + per-row label logits (272..783), verbatim =====
        AuxS& S = *reinterpret_cast<AuxS*>(smem);
        if (bid < 272) {
            int rg = t >> 4;
            int cg = (t & 15) * 8;
            const unsigned short* src;
            float* dst;
            int r0, rend;
            if (bid < 256) {
                src = wnb; dst = wsum;
                r0 = bid * 196;
                rend = r0 + 196; if (rend > Cc) rend = Cc;
            } else {
                src = embn; dst = esum;
                r0 = (bid - 256) * 128;
                rend = r0 + 128;
            }
            float acc[8];
            #pragma unroll
            for (int j = 0; j < 8; ++j) acc[j] = 0.f;
            for (int r = r0 + rg; r < rend; r += 16) {
                short8 v = *reinterpret_cast<const short8*>(src + (size_t)r * Dd + cg);
                #pragma unroll
                for (int j = 0; j < 8; ++j) acc[j] += bf2f((unsigned short)v[j]);
            }
            #pragma unroll
            for (int j = 0; j < 8; ++j) S.s[rg][cg + j] = acc[j];
            __syncthreads();
            if (t < 128) {
                float v = 0.f;
                #pragma unroll
                for (int u = 0; u < 16; ++u) v += S.s[u][t];
                atomicAdd(&dst[t], v);
            }
        } else {
            int wid = t >> 6, lane = t & 63;
            int row = (bid - 272) * 4 + wid;
            int lb = lab[row];
            const unsigned short* e = embn + (size_t)row * Dd;
            const unsigned short* wv = wnb + (size_t)lb * Dd;
            float sv = bf2f(e[lane]) * bf2f(wv[lane]) + bf2f(e[lane + 64]) * bf2f(wv[lane + 64]);
            #pragma unroll
            for (int o = 32; o > 0; o >>= 1) sv += __shfl_xor(sv, o);
            if (lane == 0) {
                float c = sv;
                float s2 = fminf(fmaxf(1.f - c * c, 0.f), 1.f);
                float sine = sqrtf(s2);
                float phi = c * COS_Mf - sine * SIN_Mf;
                phi = (c > THf) ? phi : (c - MMf);
                bx[row] = 64.f * c;
                tg[row] = 64.f * phi;
            }
        }
    } else {
        // ===== triplet: bf16 MFMA self-GEMM + masked max/min (R17, verbatim) =====
        TripS& S = *reinterpret_cast<TripS*>(smem);
        const int tb = bid - 784;
        const int w = t >> 6, l = t & 63;
        const int r0 = (tb & 15) * 128;
        const int split = tb >> 4;
        const int c0 = split * 64;
        const int rowbase = r0 + (w & 1) * 64;
        const int colb = (w >> 1) * 32;

        #pragma unroll
        for (int j = 0; j < 4; ++j) {
            int col = (w * 4 + j) * 4 + (l >> 4);
            int kb = ((l & 15) * 16) ^ ((col & 7) << 4);
            const unsigned short* src = eb + ((size_t)(c0 + col) << 7) + (kb >> 1);
            __builtin_amdgcn_global_load_lds(
                (const __attribute__((address_space(1))) void*)src,
                (__attribute__((address_space(3))) void*)(&S.swt[(w * 4 + j) * 512]),
                16, 0, 0);
        }

        short8 afrag[4][4];
        #pragma unroll
        for (int sm = 0; sm < 4; ++sm)
            #pragma unroll
            for (int kc = 0; kc < 4; ++kc) {
                int row = rowbase + sm * 16 + (l & 15);
                int k0 = kc * 32 + (l >> 4) * 8;
                afrag[sm][kc] = *reinterpret_cast<const short8*>(eb + (size_t)row * Dd + k0);
            }

        float rsq[4][4]; int rlb[4][4];
        #pragma unroll
        for (int sm = 0; sm < 4; ++sm)
            #pragma unroll
            for (int r = 0; r < 4; ++r) {
                int row = rowbase + sm * 16 + (l >> 4) * 4 + r;
                rsq[sm][r] = sqn[row];
                rlb[sm][r] = lab[row];
            }
        int cj[2]; float csq[2]; int clb[2];
        #pragma unroll
        for (int sn = 0; sn < 2; ++sn) {
            cj[sn] = c0 + colb + sn * 16 + (l & 15);
            csq[sn] = sqn[cj[sn]];
            clb[sn] = lab[cj[sn]];
        }

        __syncthreads();

        f32x4 acc[4][2];
        #pragma unroll
        for (int sm = 0; sm < 4; ++sm)
            #pragma unroll
            for (int sn = 0; sn < 2; ++sn)
                acc[sm][sn] = (f32x4){0.f, 0.f, 0.f, 0.f};

        #pragma unroll
        for (int kc = 0; kc < 4; ++kc) {
            short8 bfr[2];
            #pragma unroll
            for (int sn = 0; sn < 2; ++sn) {
                int rcol = colb + sn * 16 + (l & 15);
                int rkb = (kc * 64 + (l >> 4) * 16) ^ ((rcol & 7) << 4);
                bfr[sn] = *reinterpret_cast<const short8*>(S.swt + rcol * 128 + (rkb >> 1));
            }
            #pragma unroll
            for (int sn = 0; sn < 2; ++sn)
                #pragma unroll
                for (int sm = 0; sm < 4; ++sm)
                    acc[sm][sn] = __builtin_amdgcn_mfma_f32_16x16x32_bf16(
                        afrag[sm][kc], bfr[sn], acc[sm][sn], 0, 0, 0);
        }

        float vhp[4][4], vhn[4][4], vct[4][4];
        #pragma unroll
        for (int sm = 0; sm < 4; ++sm)
            #pragma unroll
            for (int r = 0; r < 4; ++r) { vhp[sm][r] = 0.f; vhn[sm][r] = 1e30f; vct[sm][r] = 0.f; }

        #pragma unroll
        for (int sm = 0; sm < 4; ++sm)
            #pragma unroll
            for (int r = 0; r < 4; ++r) {
                int rg = rowbase + sm * 16 + (l >> 4) * 4 + r;
                #pragma unroll
                for (int sn = 0; sn < 2; ++sn) {
                    float d2 = fmaf(acc[sm][sn][r], -2.f, rsq[sm][r] + csq[sn]);
                    float dist = sqrtf(fmaxf(d2, 0.f) + 1e-16f);
                    bool same = (rlb[sm][r] == clb[sn]);
                    bool psel = same && (rg != cj[sn]);
                    if (psel) { vhp[sm][r] = fmaxf(vhp[sm][r], dist); vct[sm][r] += 1.f; }
                    if (!same) vhn[sm][r] = fminf(vhn[sm][r], dist);
                }
            }

        #pragma unroll
        for (int sm = 0; sm < 4; ++sm)
            #pragma unroll
            for (int r = 0; r < 4; ++r) {
                float a = vhp[sm][r], b = vhn[sm][r], c = vct[sm][r];
                #pragma unroll
                for (int o = 1; o < 16; o <<= 1) {
                    a = fmaxf(a, __shfl_xor(a, o));
                    b = fminf(b, __shfl_xor(b, o));
                    c += __shfl_xor(c, o);
                }
                if ((l & 15) == 0) {
                    int row = (w & 1) * 64 + sm * 16 + (l >> 4) * 4 + r;
                    S.red[row][w >> 1][0] = a;
                    S.red[row][w >> 1][1] = b;
                    S.red[row][w >> 1][2] = c;
                }
            }
        __syncthreads();
        if (t < 128) {
            float a = fmaxf(S.red[t][0][0], S.red[t][1][0]);
            float b = fminf(S.red[t][0][1], S.red[t][1][1]);
            float c = S.red[t][0][2] + S.red[t][1][2];
            hp[(size_t)split * Bn + r0 + t] = a;
            hn[(size_t)split * Bn + r0 + t] = b;
            cnt[(size_t)split * Bn + r0 + t] = c;
        }
    }
}

// ---------------- fused bf16-MFMA cosine-GEMM + fixed-max softmax partials ----------------
// (R17-proven depth-3 per-wave private pipeline + XCD swizzle; + T5 setprio around MFMA)
__launch_bounds__(256, 3)
__global__ void arc_main(const unsigned short* __restrict__ en,
                         const unsigned short* __restrict__ wn,
                         float* __restrict__ ps) {
    __shared__ unsigned short swb[4][3][2048];   // [wave][buf][16 cols x 128 k], 48KB
    __shared__ float sred[4][64];
    const int t = threadIdx.x;
    const int w = t >> 6, l = t & 63;
    const int id = blockIdx.x;
    const int xcd = id & 7, j = id >> 3;         // j in 0..95
    const int r0 = (j / 3) * 64;                 // row-block 0..31
    const int split = xcd * 3 + (j % 3);         // 0..23
    const int strip = w * 16;                    // wave's 16-col strip within each 64-col tile
    const int lc = l & 15, lk = l >> 4;

    short8 afrag[4][4];
    #pragma unroll
    for (int sm = 0; sm < 4; ++sm)
        #pragma unroll
        for (int kc = 0; kc < 4; ++kc)
            afrag[sm][kc] = *reinterpret_cast<const short8*>(
                en + (size_t)(r0 + sm * 16 + lc) * Dd + kc * 32 + lk * 8);

    float sacc[4][4];
    #pragma unroll
    for (int sm = 0; sm < 4; ++sm)
        #pragma unroll
        for (int r = 0; r < 4; ++r) sacc[sm][r] = 0.f;

    const int ntm = (NTILE - 1 - split) / NSPL + 1;   // 32 or 33

    size_t loff[4];
    #pragma unroll
    for (int jj = 0; jj < 4; ++jj) {
        int colloc = jj * 4 + lk;
        int kb = (lc * 16) ^ ((colloc & 7) << 4);
        loff[jj] = ((size_t)(strip + colloc) << 7) + (kb >> 1);
    }

    auto STAGE = [&](unsigned short* buf, int idx) {
        int tl = split + idx * NSPL;
        if (tl > NTILE - 1) tl = NTILE - 1;
        const unsigned short* tb = wn + ((size_t)tl << 13);
        #pragma unroll
        for (int jj = 0; jj < 4; ++jj) {
            __builtin_amdgcn_global_load_lds(
                (const __attribute__((address_space(1))) void*)(tb + loff[jj]),
                (__attribute__((address_space(3))) void*)(buf + jj * 512),
                16, 0, 0);
        }
    };

    unsigned short* b0 = &swb[w][0][0];
    unsigned short* b1 = &swb[w][1][0];
    unsigned short* b2 = &swb[w][2][0];

    STAGE(b0, 0);
    STAGE(b1, 1);
    STAGE(b2, 2);

#define ASTEP(BUF, I) {                                                        \
    if ((I) < ntm) {                                                           \
        asm volatile("s_waitcnt vmcnt(8)" ::: "memory");                       \
        short8 bfr[4];                                                         \
        _Pragma("unroll")                                                      \
        for (int kc = 0; kc < 4; ++kc) {                                       \
            int rkb = (kc * 64 + lk * 16) ^ ((lc & 7) << 4);                   \
            bfr[kc] = *reinterpret_cast<const short8*>(BUF + lc * 128 + (rkb >> 1)); \
        }                                                                      \
        asm volatile("s_waitcnt lgkmcnt(0)" ::: "memory");                     \
        STAGE(BUF, (I) + 3);                                                   \
        f32x4 acc[4];                                                          \
        _Pragma("unroll")                                                      \
        for (int sm = 0; sm < 4; ++sm) acc[sm] = (f32x4){0.f, 0.f, 0.f, 0.f};  \
        __builtin_amdgcn_s_setprio(1);                                         \
        _Pragma("unroll")                                                      \
        for (int kc = 0; kc < 4; ++kc)                                         \
            _Pragma("unroll")                                                  \
            for (int sm = 0; sm < 4; ++sm)                                     \
                acc[sm] = __builtin_amdgcn_mfma_f32_16x16x32_bf16(             \
                    afrag[sm][kc], bfr[kc], acc[sm], 0, 0, 0);                 \
        __builtin_amdgcn_s_setprio(0);                                         \
        const int c0t = (split + (I) * NSPL) * 64;                             \
        if (c0t + strip < Cc) {                                                \
            _Pragma("unroll")                                                  \
            for (int sm = 0; sm < 4; ++sm)                                     \
                _Pragma("unroll")                                              \
                for (int r = 0; r < 4; ++r)                                    \
                    sacc[sm][r] += __builtin_amdgcn_exp2f(                     \
                        fmaf(acc[sm][r], L2E64, -L2E64));                      \
        }                                                                      \
    } }

    for (int ii = 0; ii < 33; ii += 3) {
        ASTEP(b0, ii);
        ASTEP(b1, ii + 1);
        ASTEP(b2, ii + 2);
    }
#undef ASTEP

    #pragma unroll
    for (int sm = 0; sm < 4; ++sm)
        #pragma unroll
        for (int r = 0; r < 4; ++r) {
            float v = sacc[sm][r];
            v += __shfl_xor(v, 1); v += __shfl_xor(v, 2);
            v += __shfl_xor(v, 4); v += __shfl_xor(v, 8);
            sacc[sm][r] = v;
        }
    if (lc == 0) {
        #pragma unroll
        for (int sm = 0; sm < 4; ++sm)
            #pragma unroll
            for (int r = 0; r < 4; ++r)
                sred[w][sm * 16 + lk * 4 + r] = sacc[sm][r];
    }
    __syncthreads();
    if (t < 64) {
        float sv = sred[0][t] + sred[1][t] + sred[2][t] + sred[3][t];
        ps[(size_t)split * Bn + r0 + t] = sv;
    }
}

// ---------------- per-row merge + last-block scalar finish (fused final) ----------------
__launch_bounds__(256)
__global__ void final_k(const float* __restrict__ ps, const float* __restrict__ bx,
                        const float* __restrict__ tg, const float* __restrict__ hp,
                        const float* __restrict__ hn, const float* __restrict__ cnt,
                        float* __restrict__ gpart, unsigned int* __restrict__ done_ct,
                        const float* __restrict__ es, const float* __restrict__ wsum,
                        float* __restrict__ out) {
    __shared__ float sA[4], sT[4], sV[4];
    __shared__ int lastf;
    int t = threadIdx.x;
    int row = blockIdx.x * 64 + (t >> 2);
    int part = t & 3;
    float s = 0.f;
    for (int u = part; u < NSPL; u += 4) s += ps[(size_t)u * Bn + row];
    float a = 0.f, b = 1e30f, c = 0.f;
    for (int u = part; u < TS; u += 4) {
        a = fmaxf(a, hp[(size_t)u * Bn + row]);
        b = fminf(b, hn[(size_t)u * Bn + row]);
        c += cnt[(size_t)u * Bn + row];
    }
    s += __shfl_xor(s, 1); s += __shfl_xor(s, 2);
    a = fmaxf(a, __shfl_xor(a, 1)); a = fmaxf(a, __shfl_xor(a, 2));
    b = fminf(b, __shfl_xor(b, 1)); b = fminf(b, __shfl_xor(b, 2));
    c += __shfl_xor(c, 1); c += __shfl_xor(c, 2);

    float arcs = 0.f, tris = 0.f, vals = 0.f;
    if (part == 0) {
        float base = bx[row], targ = tg[row];
        s += __expf(targ - 64.f) - __expf(base - 64.f);
        float lse = 64.f + logf(s);
        arcs = lse - 0.9f * targ - 0.1f * (targ - base) / (float)Cc;
        float tl = fmaxf(a - b + 0.3f, 0.f);
        tris = (c > 0.f) ? tl : 0.f;
        vals = (c > 0.f) ? 1.f : 0.f;
    }

    #pragma unroll
    for (int o = 32; o > 0; o >>= 1) {
        arcs += __shfl_xor(arcs, o);
        tris += __shfl_xor(tris, o);
        vals += __shfl_xor(vals, o);
    }
    int wid = t >> 6, lane = t & 63;
    if (lane == 0) { sA[wid] = arcs; sT[wid] = tris; sV[wid] = vals; }
    __syncthreads();
    if (t == 0) {
        gpart[blockIdx.x * 3 + 0] = sA[0] + sA[1] + sA[2] + sA[3];
        gpart[blockIdx.x * 3 + 1] = sT[0] + sT[1] + sT[2] + sT[3];
        gpart[blockIdx.x * 3 + 2] = sV[0] + sV[1] + sV[2] + sV[3];
        __threadfence();
        unsigned int old = atomicAdd(done_ct, 1u);
        lastf = (old == 31u) ? 1 : 0;
    }
    __syncthreads();
    if (lastf && t < 64) {
        __threadfence();   // acquire side: make all blocks' gpart stores visible
        int l = t;
        float x = es[l] * wsum[l] + es[l + 64] * wsum[l + 64];
        #pragma unroll
        for (int o = 32; o > 0; o >>= 1) x += __shfl_xor(x, o);
        float A = 0.f, T = 0.f, V = 0.f;
        if (l < 32) {
            A = gpart[l * 3 + 0];
            T = gpart[l * 3 + 1];
            V = gpart[l * 3 + 2];
        }
        #pragma unroll
        for (int o = 32; o > 0; o >>= 1) {
            A += __shfl_xor(A, o);
            T += __shfl_xor(T, o);
            V += __shfl_xor(V, o);
        }
        if (l == 0) {
            float tri = (V > 0.f) ? (T / fmaxf(V, 1.f)) : 0.f;
            out[0] = (A - 6.4f * x / (float)Cc) / (float)Bn + 0.5f * tri;
        }
    }
}

extern "C" void kernel_launch(void* const* d_in, const int* in_sizes, int n_in,
                              void* d_out, int out_size, void* d_ws, size_t ws_size,
                              hipStream_t stream) {
    const float* emb = (const float*)d_in[0];
    const float* W = (const float*)d_in[1];
    const int* lab = (const int*)d_in[2];
    float* out = (float*)d_out;

    unsigned short* embn = (unsigned short*)d_ws;          // 2048*128 bf16
    unsigned short* rawb = embn + (size_t)Bn * Dd;         // 2048*128 bf16
    unsigned short* wnb = rawb + (size_t)Bn * Dd;          // 50000*128 bf16
    float* sqn = (float*)(wnb + (size_t)Cc * Dd);          // 2048
    float* ps = sqn + Bn;                                  // NSPL*2048
    float* bx = ps + (size_t)NSPL * Bn;                    // 2048
    float* tg = bx + Bn;                                   // 2048
    float* hp = tg + Bn;                                   // TS*2048
    float* hn = hp + (size_t)TS * Bn;                      // TS*2048
    float* ct = hn + (size_t)TS * Bn;                      // TS*2048
    float* esum = ct + (size_t)TS * Bn;                    // 128
    float* wsum = esum + 128;                              // 128
    float* gpart = wsum + 128;                             // 96
    unsigned int* done_ct = (unsigned int*)(gpart + 96);   // 1

    norm_all<<<256 + Cc / 8, 256, 0, stream>>>(emb, W, embn, rawb, sqn, wnb, esum, done_ct);
    mid_k<<<784 + 512, 256, 0, stream>>>(embn, wnb, lab, esum, wsum, bx, tg,
                                         rawb, sqn, hp, hn, ct);
    arc_main<<<768, 256, 0, stream>>>(embn, wnb, ps);
    final_k<<<32, 256, 0, stream>>>(ps, bx, tg, hp, hn, ct, gpart, done_ct,
                                    esum, wsum, out);
}